// Round 2
// baseline (739.565 us; speedup 1.0000x reference)
//
#include <hip/hip_runtime.h>
#include <stdint.h>
#include <stddef.h>

// EdgeLearning: out[e] = W2 @ leaky(W1 @ [x[ei0[e]], x[ei1[e]], ea[e]] + b1) + b2
// bf16 MFMA 16x16x32, fp32 accumulate.
//
// Key structure (R1): layer 1 computed with W1 as A-operand, mask as B-operand,
// so h lands with col=lane&15=e, row=q*4+r=h-dim. Layer 2 then uses a PERMUTED
// k-order k'=q*8+j -> (j<4 ? 32c+q*4+j : 32c+16+q*4+(j-4)); with W2 fragments
// loaded with the same permutation, each lane's B-fragment for layer 2 is just
// a register-local bf16 pack of its own h values — no LDS round-trip, no
// cross-lane ops. Output lands row=o, col=e -> f32x4 vectorized stores.
// LDS: W1 (bf16, rows padded 160->168 for 16B-aligned conflict-free b128
// reads) + f32 copies of b1/b2 (broadcast reads) = 43776 B -> 3 blocks/CU.

typedef short short8 __attribute__((ext_vector_type(8)));
typedef short bf4 __attribute__((ext_vector_type(4)));
typedef float f32x4 __attribute__((ext_vector_type(4)));

#define TILES_PER_BLOCK 4

__device__ __forceinline__ short f2bf(float f) {
  union { float f; unsigned u; } v; v.f = f;
  unsigned r = (v.u + 0x7fffu + ((v.u >> 16) & 1u)) >> 16;  // RNE
  return (short)r;
}

__device__ __forceinline__ short8 cvt8(const float* __restrict__ p) {
  f32x4 a = *(const f32x4*)p;
  f32x4 b = *(const f32x4*)(p + 4);
  short8 r;
  r[0] = f2bf(a[0]); r[1] = f2bf(a[1]); r[2] = f2bf(a[2]); r[3] = f2bf(a[3]);
  r[4] = f2bf(b[0]); r[5] = f2bf(b[1]); r[6] = f2bf(b[2]); r[7] = f2bf(b[3]);
  return r;
}

// nontemporal: streamed read-once data (edge_attr) — keep it out of L2 so the
// x-gather working set keeps its L2 residency.
__device__ __forceinline__ short8 cvt8_nt(const float* __restrict__ p) {
  f32x4 a = __builtin_nontemporal_load((const f32x4*)p);
  f32x4 b = __builtin_nontemporal_load((const f32x4*)(p + 4));
  short8 r;
  r[0] = f2bf(a[0]); r[1] = f2bf(a[1]); r[2] = f2bf(a[2]); r[3] = f2bf(a[3]);
  r[4] = f2bf(b[0]); r[5] = f2bf(b[1]); r[6] = f2bf(b[2]); r[7] = f2bf(b[3]);
  return r;
}

__global__ __launch_bounds__(256, 3)
void edge_mlp(const float* __restrict__ x, const int* __restrict__ ei,
              const float* __restrict__ ea, const float* __restrict__ W1,
              const float* __restrict__ b1, const float* __restrict__ W2,
              const float* __restrict__ b2, float* __restrict__ out,
              int E, int ntiles)
{
  __shared__ short sW1[128 * 168];
  __shared__ float sB1[128];
  __shared__ float sB2[64];

  const int tid  = threadIdx.x;
  const int lane = tid & 63;
  const int wave = tid >> 6;
  const int m    = lane & 15;
  const int q    = lane >> 4;

  // Stage W1 -> LDS as bf16 (vectorized: 40 f32x4 groups per row)
  for (int i = tid; i < 128 * 40; i += 256) {
    int n  = i / 40;
    int k4 = (i - n * 40) * 4;
    f32x4 v = *(const f32x4*)(W1 + n * 160 + k4);
    bf4 s; s[0] = f2bf(v[0]); s[1] = f2bf(v[1]); s[2] = f2bf(v[2]); s[3] = f2bf(v[3]);
    *(bf4*)&sW1[n * 168 + k4] = s;
  }
  if (tid < 128) sB1[tid] = b1[tid];
  if (tid < 64)  sB2[tid] = b2[tid];

  // W2 fragments, A-layout with the permuted k-order:
  // A2[o=ot*16+m][k'=q*8+j]: j<4 -> W2[o][c*32+q*4+j]; j>=4 -> W2[o][c*32+16+q*4+(j-4)]
  short8 w2f[4][4];
#pragma unroll
  for (int ot = 0; ot < 4; ++ot)
#pragma unroll
    for (int c = 0; c < 4; ++c) {
      const float* base = W2 + (size_t)(ot * 16 + m) * 128 + c * 32 + q * 4;
      f32x4 lo = *(const f32x4*)base;
      f32x4 hi = *(const f32x4*)(base + 16);
      short8 w;
      w[0] = f2bf(lo[0]); w[1] = f2bf(lo[1]); w[2] = f2bf(lo[2]); w[3] = f2bf(lo[3]);
      w[4] = f2bf(hi[0]); w[5] = f2bf(hi[1]); w[6] = f2bf(hi[2]); w[7] = f2bf(hi[3]);
      w2f[ot][c] = w;
    }

  __syncthreads();

  const int t0   = blockIdx.x * TILES_PER_BLOCK;
  const int tend = (t0 + TILES_PER_BLOCK < ntiles) ? t0 + TILES_PER_BLOCK : ntiles;
  if (t0 >= ntiles) return;

  // Software-pipelined edge-index loads (break idx -> gather -> MFMA chain)
  int nI0[2], nI1[2];
  {
    const int eb = t0 * 128 + wave * 32;
#pragma unroll
    for (int mt = 0; mt < 2; ++mt) {
      int e = eb + mt * 16 + m; e = (e < E) ? e : (E - 1);
      nI0[mt] = ei[e]; nI1[mt] = ei[E + e];
    }
  }

  for (int t = t0; t < tend; ++t) {
    const int eb = t * 128 + wave * 32;
    const int cI0[2] = { nI0[0], nI0[1] };
    const int cI1[2] = { nI1[0], nI1[1] };
    if (t + 1 < tend) {
      const int eb2 = eb + 128;
#pragma unroll
      for (int mt = 0; mt < 2; ++mt) {
        int e = eb2 + mt * 16 + m; e = (e < E) ? e : (E - 1);
        nI0[mt] = ei[e]; nI1[mt] = ei[E + e];
      }
    }

    // Gather mask rows as layer-1 B fragments: B1[n=e][k], k = kt*32 + q*8 + j
    short8 a1[2][5];
#pragma unroll
    for (int mt = 0; mt < 2; ++mt) {
      int e = eb + mt * 16 + m; e = (e < E) ? e : (E - 1);
      const float* r0 = x + (size_t)cI0[mt] * 64 + q * 8;
      const float* r1 = x + (size_t)cI1[mt] * 64 + q * 8;
      a1[mt][0] = cvt8(r0);
      a1[mt][1] = cvt8(r0 + 32);
      a1[mt][2] = cvt8(r1);
      a1[mt][3] = cvt8(r1 + 32);
      a1[mt][4] = cvt8_nt(ea + (size_t)e * 32 + q * 8);
    }

    // acc2 init = b2 broadcast: D2 row = o = ot*16 + q*4 + r
    f32x4 acc2[2][4];
#pragma unroll
    for (int ot = 0; ot < 4; ++ot) {
      f32x4 bb = *(const f32x4*)&sB2[ot * 16 + q * 4];
      acc2[0][ot] = bb; acc2[1][ot] = bb;
    }

#pragma unroll
    for (int c = 0; c < 4; ++c) {
      f32x4 hs[2][2];  // [sub][mt]: h[e=m][n_h = (2c+sub)*16 + q*4 + r]
#pragma unroll
      for (int sub = 0; sub < 2; ++sub) {
        const int nt = c * 2 + sub;
        f32x4 binit = *(const f32x4*)&sB1[nt * 16 + q * 4];
        f32x4 h0 = binit, h1 = binit;
#pragma unroll
        for (int kt = 0; kt < 5; ++kt) {
          short8 wf = *(const short8*)&sW1[(nt * 16 + m) * 168 + kt * 32 + q * 8];
          h0 = __builtin_amdgcn_mfma_f32_16x16x32_bf16(wf, a1[0][kt], h0, 0, 0, 0);
          h1 = __builtin_amdgcn_mfma_f32_16x16x32_bf16(wf, a1[1][kt], h1, 0, 0, 0);
        }
        hs[sub][0] = h0; hs[sub][1] = h1;
      }
      // leaky + pack own registers as layer-2 B fragment (k-permuted, no LDS)
#pragma unroll
      for (int mt = 0; mt < 2; ++mt) {
        short8 hb;
#pragma unroll
        for (int sub = 0; sub < 2; ++sub)
#pragma unroll
          for (int r = 0; r < 4; ++r) {
            float v = hs[sub][mt][r];
            v = (v >= 0.0f) ? v : 0.01f * v;
            hb[sub * 4 + r] = f2bf(v);
          }
#pragma unroll
        for (int ot = 0; ot < 4; ++ot)
          acc2[mt][ot] = __builtin_amdgcn_mfma_f32_16x16x32_bf16(w2f[ot][c], hb, acc2[mt][ot], 0, 0, 0);
      }
    }

    // Store: lane holds out[e = eb + mt*16 + m][o = ot*16 + q*4 + r] -> f32x4
#pragma unroll
    for (int mt = 0; mt < 2; ++mt) {
      int e = eb + mt * 16 + m;
      if (e < E) {
        float* op = out + (size_t)e * 64 + q * 4;
#pragma unroll
        for (int ot = 0; ot < 4; ++ot)
          __builtin_nontemporal_store(acc2[mt][ot], (f32x4*)(op + ot * 16));
      }
    }
  }
}

extern "C" void kernel_launch(void* const* d_in, const int* in_sizes, int n_in,
                              void* d_out, int out_size, void* d_ws, size_t ws_size,
                              hipStream_t stream) {
  const float* x  = (const float*)d_in[0];
  const int*   ei = (const int*)d_in[1];
  const float* ea = (const float*)d_in[2];
  const float* W1 = (const float*)d_in[3];
  const float* b1 = (const float*)d_in[4];
  const float* W2 = (const float*)d_in[5];
  const float* b2 = (const float*)d_in[6];
  float* out = (float*)d_out;

  const int E = in_sizes[1] / 2;            // edge_index is [2, E]
  const int ntiles = (E + 127) / 128;       // 128 edges per block-tile
  const int grid = (ntiles + TILES_PER_BLOCK - 1) / TILES_PER_BLOCK;

  edge_mlp<<<grid, 256, 0, stream>>>(x, ei, ea, W1, b1, W2, b2, out, E, ntiles);
}

// Round 3
// 715.846 us; speedup vs baseline: 1.0331x; 1.0331x over previous
//
#include <hip/hip_runtime.h>
#include <stdint.h>
#include <stddef.h>

// EdgeLearning: out[e] = W2 @ leaky(W1 @ [x[ei0[e]], x[ei1[e]], ea[e]] + b1) + b2
// bf16 MFMA 16x16x32, fp32 accumulate.
//
// Structure (validated R2): layer 1 computed with W1 as A-operand, mask as
// B-operand, so h lands with col=lane&15=e, row=q*4+r=h-dim. Layer 2 uses a
// PERMUTED k-order k'=q*8+j -> (j<4 ? 32c+q*4+j : 32c+16+q*4+(j-4)); with W2
// fragments loaded with the same permutation, each lane's layer-2 B-fragment
// is a register-local bf16 pack of its own h values — no LDS round-trip, no
// cross-lane ops. Output lands row=o, col=e -> f32x4 vectorized stores.
//
// R3: NO nontemporal hints (R2 showed NT stores 3.2x WRITE_SIZE via partial
// HBM lines, NT loads ~5x FETCH_SIZE — L2 write-combining/line-assembly is
// what keeps us at the 200MB/230MB compulsory traffic). Persistent grid:
// 768 blocks = 3 blocks/CU (LDS-bound residency), grid-stride tile loop, no
// partial-generation tail; idx prefetch at t+gridDim.
// LDS: W1 bf16 rows padded 160->168 (16B-aligned b128 reads, 2-way-free bank
// pattern) + f32 b1/b2 = 44032 B -> 3 blocks/CU.

typedef short short8 __attribute__((ext_vector_type(8)));
typedef short bf4 __attribute__((ext_vector_type(4)));
typedef float f32x4 __attribute__((ext_vector_type(4)));

__device__ __forceinline__ short f2bf(float f) {
  union { float f; unsigned u; } v; v.f = f;
  unsigned r = (v.u + 0x7fffu + ((v.u >> 16) & 1u)) >> 16;  // RNE
  return (short)r;
}

__device__ __forceinline__ short8 cvt8(const float* __restrict__ p) {
  f32x4 a = *(const f32x4*)p;
  f32x4 b = *(const f32x4*)(p + 4);
  short8 r;
  r[0] = f2bf(a[0]); r[1] = f2bf(a[1]); r[2] = f2bf(a[2]); r[3] = f2bf(a[3]);
  r[4] = f2bf(b[0]); r[5] = f2bf(b[1]); r[6] = f2bf(b[2]); r[7] = f2bf(b[3]);
  return r;
}

__global__ __launch_bounds__(256, 3)
void edge_mlp(const float* __restrict__ x, const int* __restrict__ ei,
              const float* __restrict__ ea, const float* __restrict__ W1,
              const float* __restrict__ b1, const float* __restrict__ W2,
              const float* __restrict__ b2, float* __restrict__ out,
              int E, int ntiles)
{
  __shared__ short sW1[128 * 168];
  __shared__ float sB1[128];
  __shared__ float sB2[64];

  const int tid  = threadIdx.x;
  const int lane = tid & 63;
  const int wave = tid >> 6;
  const int m    = lane & 15;
  const int q    = lane >> 4;

  // Stage W1 -> LDS as bf16 (vectorized: 40 f32x4 groups per row)
  for (int i = tid; i < 128 * 40; i += 256) {
    int n  = i / 40;
    int k4 = (i - n * 40) * 4;
    f32x4 v = *(const f32x4*)(W1 + n * 160 + k4);
    bf4 s; s[0] = f2bf(v[0]); s[1] = f2bf(v[1]); s[2] = f2bf(v[2]); s[3] = f2bf(v[3]);
    *(bf4*)&sW1[n * 168 + k4] = s;
  }
  if (tid < 128) sB1[tid] = b1[tid];
  if (tid < 64)  sB2[tid] = b2[tid];

  // W2 fragments, A-layout with the permuted k-order:
  // A2[o=ot*16+m][k'=q*8+j]: j<4 -> W2[o][c*32+q*4+j]; j>=4 -> W2[o][c*32+16+q*4+(j-4)]
  short8 w2f[4][4];
#pragma unroll
  for (int ot = 0; ot < 4; ++ot)
#pragma unroll
    for (int c = 0; c < 4; ++c) {
      const float* base = W2 + (size_t)(ot * 16 + m) * 128 + c * 32 + q * 4;
      f32x4 lo = *(const f32x4*)base;
      f32x4 hi = *(const f32x4*)(base + 16);
      short8 w;
      w[0] = f2bf(lo[0]); w[1] = f2bf(lo[1]); w[2] = f2bf(lo[2]); w[3] = f2bf(lo[3]);
      w[4] = f2bf(hi[0]); w[5] = f2bf(hi[1]); w[6] = f2bf(hi[2]); w[7] = f2bf(hi[3]);
      w2f[ot][c] = w;
    }

  __syncthreads();

  int t = blockIdx.x;
  if (t >= ntiles) return;

  // Software-pipelined edge-index loads (break idx -> gather -> MFMA chain)
  int nI0[2], nI1[2];
  {
    const int eb = t * 128 + wave * 32;
#pragma unroll
    for (int mt = 0; mt < 2; ++mt) {
      int e = eb + mt * 16 + m; e = (e < E) ? e : (E - 1);
      nI0[mt] = ei[e]; nI1[mt] = ei[E + e];
    }
  }

  for (; t < ntiles; t += gridDim.x) {
    const int eb = t * 128 + wave * 32;
    const int cI0[2] = { nI0[0], nI0[1] };
    const int cI1[2] = { nI1[0], nI1[1] };
    const int tn = t + gridDim.x;
    if (tn < ntiles) {
      const int eb2 = tn * 128 + wave * 32;
#pragma unroll
      for (int mt = 0; mt < 2; ++mt) {
        int e = eb2 + mt * 16 + m; e = (e < E) ? e : (E - 1);
        nI0[mt] = ei[e]; nI1[mt] = ei[E + e];
      }
    }

    // Gather mask rows as layer-1 B fragments: B1[n=e][k], k = kt*32 + q*8 + j
    short8 a1[2][5];
#pragma unroll
    for (int mt = 0; mt < 2; ++mt) {
      int e = eb + mt * 16 + m; e = (e < E) ? e : (E - 1);
      const float* r0 = x + (size_t)cI0[mt] * 64 + q * 8;
      const float* r1 = x + (size_t)cI1[mt] * 64 + q * 8;
      a1[mt][0] = cvt8(r0);
      a1[mt][1] = cvt8(r0 + 32);
      a1[mt][2] = cvt8(r1);
      a1[mt][3] = cvt8(r1 + 32);
      a1[mt][4] = cvt8(ea + (size_t)e * 32 + q * 8);
    }

    // acc2 init = b2 broadcast: D2 row = o = ot*16 + q*4 + r
    f32x4 acc2[2][4];
#pragma unroll
    for (int ot = 0; ot < 4; ++ot) {
      f32x4 bb = *(const f32x4*)&sB2[ot * 16 + q * 4];
      acc2[0][ot] = bb; acc2[1][ot] = bb;
    }

#pragma unroll
    for (int c = 0; c < 4; ++c) {
      short8 hb[2];  // layer-2 B fragment per m-tile (own-register pack)
#pragma unroll
      for (int sub = 0; sub < 2; ++sub) {
        const int nt = c * 2 + sub;
        f32x4 binit = *(const f32x4*)&sB1[nt * 16 + q * 4];
        f32x4 h0 = binit, h1 = binit;
#pragma unroll
        for (int kt = 0; kt < 5; ++kt) {
          short8 wf = *(const short8*)&sW1[(nt * 16 + m) * 168 + kt * 32 + q * 8];
          h0 = __builtin_amdgcn_mfma_f32_16x16x32_bf16(wf, a1[0][kt], h0, 0, 0, 0);
          h1 = __builtin_amdgcn_mfma_f32_16x16x32_bf16(wf, a1[1][kt], h1, 0, 0, 0);
        }
        // leaky + pack into the permuted-k B fragment (frees h regs early)
#pragma unroll
        for (int r = 0; r < 4; ++r) {
          float v0 = h0[r]; v0 = (v0 >= 0.0f) ? v0 : 0.01f * v0;
          float v1 = h1[r]; v1 = (v1 >= 0.0f) ? v1 : 0.01f * v1;
          hb[0][sub * 4 + r] = f2bf(v0);
          hb[1][sub * 4 + r] = f2bf(v1);
        }
      }
#pragma unroll
      for (int mt = 0; mt < 2; ++mt)
#pragma unroll
        for (int ot = 0; ot < 4; ++ot)
          acc2[mt][ot] = __builtin_amdgcn_mfma_f32_16x16x32_bf16(w2f[ot][c], hb[mt], acc2[mt][ot], 0, 0, 0);
    }

    // Store: lane holds out[e = eb + mt*16 + m][o = ot*16 + q*4 + r] -> f32x4
#pragma unroll
    for (int mt = 0; mt < 2; ++mt) {
      int e = eb + mt * 16 + m;
      if (e < E) {
        float* op = out + (size_t)e * 64 + q * 4;
#pragma unroll
        for (int ot = 0; ot < 4; ++ot)
          *(f32x4*)(op + ot * 16) = acc2[mt][ot];
      }
    }
  }
}

extern "C" void kernel_launch(void* const* d_in, const int* in_sizes, int n_in,
                              void* d_out, int out_size, void* d_ws, size_t ws_size,
                              hipStream_t stream) {
  const float* x  = (const float*)d_in[0];
  const int*   ei = (const int*)d_in[1];
  const float* ea = (const float*)d_in[2];
  const float* W1 = (const float*)d_in[3];
  const float* b1 = (const float*)d_in[4];
  const float* W2 = (const float*)d_in[5];
  const float* b2 = (const float*)d_in[6];
  float* out = (float*)d_out;

  const int E = in_sizes[1] / 2;          // edge_index is [2, E]
  const int ntiles = (E + 127) / 128;     // 128 edges per tile (32 per wave)
  const int grid = ntiles < 768 ? ntiles : 768;  // 3 blocks/CU persistent

  edge_mlp<<<grid, 256, 0, stream>>>(x, ei, ea, W1, b1, W2, b2, out, E, ntiles);
}

// Round 4
// 590.844 us; speedup vs baseline: 1.2517x; 1.2116x over previous
//
#include <hip/hip_runtime.h>
#include <stdint.h>
#include <stddef.h>

// EdgeLearning: out[e] = W2 @ leaky(W1 @ [x[ei0[e]], x[ei1[e]], ea[e]] + b1) + b2
// bf16 MFMA 16x16x32, fp32 accumulate.
//
// Structure (validated R2/R3): layer 1 computed with W1 as A-operand, mask as
// B-operand, so h lands with col=lane&15=e, row=q*4+r=h-dim. Layer 2 uses a
// PERMUTED k-order k'=q*8+j -> (j<4 ? 32c+q*4+j : 32c+16+q*4+(j-4)); with W2
// fragments loaded with the same permutation, each lane's layer-2 B-fragment
// is a register-local bf16 pack of its own h values — no LDS round-trip, no
// cross-lane ops. Output lands row=o, col=e -> f32x4 vectorized stores.
//
// R4 fixes (from R3 counters):
//  * __launch_bounds__(256,2): R3's (256,3) capped VGPRs at ~170 -> allocator
//    spilled w2f/a1 to scratch (VGPR_Count=84, FETCH 1.1GB, WRITE 410MB =
//    spill traffic). Live state needs ~215 regs; cap 256 avoids all spills.
//  * Gather double-buffer: a1 for tile t+grid prefetched during tile t
//    (indices prefetched two strides ahead), hiding ~900cyc gather latency.
//  * v_cvt_pk_bf16_f32 (gfx950) for f32->bf16: 1 VALU op per 2 values vs ~5.
//  * grid=512 = 2 blocks/CU exactly (VGPR-bound residency), uniform work.
// NO nontemporal hints (R2: NT stores 3.2x WRITE via partial lines, NT loads
// defeat L2 line assembly). LDS: W1 bf16 rows padded 160->168 + b1/b2 = 44KB.

typedef short short8 __attribute__((ext_vector_type(8)));
typedef short bf4 __attribute__((ext_vector_type(4)));
typedef float f32x4 __attribute__((ext_vector_type(4)));
typedef short short2v __attribute__((ext_vector_type(2)));
typedef __bf16 bf16x2 __attribute__((ext_vector_type(2)));

__device__ __forceinline__ short f2bf(float f) {
  union { float f; unsigned u; } v; v.f = f;
  unsigned r = (v.u + 0x7fffu + ((v.u >> 16) & 1u)) >> 16;  // RNE
  return (short)r;
}

__device__ __forceinline__ short2v pk2(float a, float b) {
#if __has_builtin(__builtin_amdgcn_cvt_pk_bf16_f32)
  bf16x2 t = __builtin_amdgcn_cvt_pk_bf16_f32(a, b);
  union { bf16x2 b; short2v s; } u; u.b = t;
  return u.s;
#else
  short2v r; r[0] = f2bf(a); r[1] = f2bf(b); return r;
#endif
}

__device__ __forceinline__ short8 cvt8(const float* __restrict__ p) {
  f32x4 a = *(const f32x4*)p;
  f32x4 b = *(const f32x4*)(p + 4);
  short2v t0 = pk2(a[0], a[1]), t1 = pk2(a[2], a[3]);
  short2v t2 = pk2(b[0], b[1]), t3 = pk2(b[2], b[3]);
  short8 r;
  r[0] = t0[0]; r[1] = t0[1]; r[2] = t1[0]; r[3] = t1[1];
  r[4] = t2[0]; r[5] = t2[1]; r[6] = t3[0]; r[7] = t3[1];
  return r;
}

__global__ __launch_bounds__(256, 2)
void edge_mlp(const float* __restrict__ x, const int* __restrict__ ei,
              const float* __restrict__ ea, const float* __restrict__ W1,
              const float* __restrict__ b1, const float* __restrict__ W2,
              const float* __restrict__ b2, float* __restrict__ out,
              int E, int ntiles)
{
  __shared__ short sW1[128 * 168];
  __shared__ float sB1[128];
  __shared__ float sB2[64];

  const int tid  = threadIdx.x;
  const int lane = tid & 63;
  const int wave = tid >> 6;
  const int m    = lane & 15;
  const int q    = lane >> 4;

  // Stage W1 -> LDS as bf16
  for (int i = tid; i < 128 * 40; i += 256) {
    int n  = i / 40;
    int k4 = (i - n * 40) * 4;
    f32x4 v = *(const f32x4*)(W1 + n * 160 + k4);
    short2v lo = pk2(v[0], v[1]), hi = pk2(v[2], v[3]);
    bf4 s; s[0] = lo[0]; s[1] = lo[1]; s[2] = hi[0]; s[3] = hi[1];
    *(bf4*)&sW1[n * 168 + k4] = s;
  }
  if (tid < 128) sB1[tid] = b1[tid];
  if (tid < 64)  sB2[tid] = b2[tid];

  // W2 fragments, A-layout with the permuted k-order:
  // A2[o=ot*16+m][k'=q*8+j]: j<4 -> W2[o][c*32+q*4+j]; j>=4 -> W2[o][c*32+16+q*4+(j-4)]
  short8 w2f[4][4];
#pragma unroll
  for (int ot = 0; ot < 4; ++ot)
#pragma unroll
    for (int c = 0; c < 4; ++c) {
      const float* base = W2 + (size_t)(ot * 16 + m) * 128 + c * 32 + q * 4;
      f32x4 lo = *(const f32x4*)base;
      f32x4 hi = *(const f32x4*)(base + 16);
      short2v p0 = pk2(lo[0], lo[1]), p1 = pk2(lo[2], lo[3]);
      short2v p2 = pk2(hi[0], hi[1]), p3 = pk2(hi[2], hi[3]);
      short8 w;
      w[0] = p0[0]; w[1] = p0[1]; w[2] = p1[0]; w[3] = p1[1];
      w[4] = p2[0]; w[5] = p2[1]; w[6] = p3[0]; w[7] = p3[1];
      w2f[ot][c] = w;
    }

  __syncthreads();

  int t = blockIdx.x;
  if (t >= ntiles) return;
  const int g = gridDim.x;

  // ---- software pipeline: a1 gathers one tile ahead, indices two ahead ----
  int cI0[2], cI1[2], nI0[2], nI1[2];
  short8 a1[2][5];

  {
    const int eb = t * 128 + wave * 32;
#pragma unroll
    for (int mt = 0; mt < 2; ++mt) {
      int e = eb + mt * 16 + m; e = (e < E) ? e : (E - 1);
      cI0[mt] = ei[e]; cI1[mt] = ei[E + e];
    }
#pragma unroll
    for (int mt = 0; mt < 2; ++mt) {
      int e = eb + mt * 16 + m; e = (e < E) ? e : (E - 1);
      const float* r0 = x + (size_t)cI0[mt] * 64 + q * 8;
      const float* r1 = x + (size_t)cI1[mt] * 64 + q * 8;
      a1[mt][0] = cvt8(r0);
      a1[mt][1] = cvt8(r0 + 32);
      a1[mt][2] = cvt8(r1);
      a1[mt][3] = cvt8(r1 + 32);
      a1[mt][4] = cvt8(ea + (size_t)e * 32 + q * 8);
    }
    if (t + g < ntiles) {
      const int eb2 = (t + g) * 128 + wave * 32;
#pragma unroll
      for (int mt = 0; mt < 2; ++mt) {
        int e = eb2 + mt * 16 + m; e = (e < E) ? e : (E - 1);
        nI0[mt] = ei[e]; nI1[mt] = ei[E + e];
      }
    } else {
      nI0[0] = nI0[1] = nI1[0] = nI1[1] = 0;
    }
  }

  for (; t < ntiles; t += g) {
    const int eb = t * 128 + wave * 32;
    const int tn = t + g;

    // Issue next tile's gathers + next-next indices (in flight during compute)
    short8 a1n[2][5];
    int nnI0[2], nnI1[2];
    if (tn < ntiles) {
      const int eb2 = tn * 128 + wave * 32;
#pragma unroll
      for (int mt = 0; mt < 2; ++mt) {
        int e = eb2 + mt * 16 + m; e = (e < E) ? e : (E - 1);
        const float* r0 = x + (size_t)nI0[mt] * 64 + q * 8;
        const float* r1 = x + (size_t)nI1[mt] * 64 + q * 8;
        a1n[mt][0] = cvt8(r0);
        a1n[mt][1] = cvt8(r0 + 32);
        a1n[mt][2] = cvt8(r1);
        a1n[mt][3] = cvt8(r1 + 32);
        a1n[mt][4] = cvt8(ea + (size_t)e * 32 + q * 8);
      }
      if (tn + g < ntiles) {
        const int eb3 = (tn + g) * 128 + wave * 32;
#pragma unroll
        for (int mt = 0; mt < 2; ++mt) {
          int e = eb3 + mt * 16 + m; e = (e < E) ? e : (E - 1);
          nnI0[mt] = ei[e]; nnI1[mt] = ei[E + e];
        }
      }
    }

    // acc2 init = b2 broadcast: D2 row = o = ot*16 + q*4 + r
    f32x4 acc2[2][4];
#pragma unroll
    for (int ot = 0; ot < 4; ++ot) {
      f32x4 bb = *(const f32x4*)&sB2[ot * 16 + q * 4];
      acc2[0][ot] = bb; acc2[1][ot] = bb;
    }

#pragma unroll
    for (int c = 0; c < 4; ++c) {
      short8 hb[2];  // layer-2 B fragment per m-tile (own-register pack)
#pragma unroll
      for (int sub = 0; sub < 2; ++sub) {
        const int nt = c * 2 + sub;
        f32x4 binit = *(const f32x4*)&sB1[nt * 16 + q * 4];
        f32x4 h0 = binit, h1 = binit;
#pragma unroll
        for (int kt = 0; kt < 5; ++kt) {
          short8 wf = *(const short8*)&sW1[(nt * 16 + m) * 168 + kt * 32 + q * 8];
          h0 = __builtin_amdgcn_mfma_f32_16x16x32_bf16(wf, a1[0][kt], h0, 0, 0, 0);
          h1 = __builtin_amdgcn_mfma_f32_16x16x32_bf16(wf, a1[1][kt], h1, 0, 0, 0);
        }
        // leaky + pack into the permuted-k B fragment
#pragma unroll
        for (int r = 0; r < 4; ++r) {
          float v0 = h0[r]; v0 = (v0 >= 0.0f) ? v0 : 0.01f * v0;
          float v1 = h1[r]; v1 = (v1 >= 0.0f) ? v1 : 0.01f * v1;
          short2v pv = pk2(v0, v1);
          hb[0][sub * 4 + r] = pv[0];
          hb[1][sub * 4 + r] = pv[1];
        }
      }
#pragma unroll
      for (int mt = 0; mt < 2; ++mt)
#pragma unroll
        for (int ot = 0; ot < 4; ++ot)
          acc2[mt][ot] = __builtin_amdgcn_mfma_f32_16x16x32_bf16(w2f[ot][c], hb[mt], acc2[mt][ot], 0, 0, 0);
    }

    // Store: lane holds out[e = eb + mt*16 + m][o = ot*16 + q*4 + r] -> f32x4
#pragma unroll
    for (int mt = 0; mt < 2; ++mt) {
      int e = eb + mt * 16 + m;
      if (e < E) {
        float* op = out + (size_t)e * 64 + q * 4;
#pragma unroll
        for (int ot = 0; ot < 4; ++ot)
          *(f32x4*)(op + ot * 16) = acc2[mt][ot];
      }
    }

    // rotate pipeline registers
#pragma unroll
    for (int mt = 0; mt < 2; ++mt) {
#pragma unroll
      for (int kt = 0; kt < 5; ++kt) a1[mt][kt] = a1n[mt][kt];
      nI0[mt] = nnI0[mt]; nI1[mt] = nnI1[mt];
    }
  }
}

extern "C" void kernel_launch(void* const* d_in, const int* in_sizes, int n_in,
                              void* d_out, int out_size, void* d_ws, size_t ws_size,
                              hipStream_t stream) {
  const float* x  = (const float*)d_in[0];
  const int*   ei = (const int*)d_in[1];
  const float* ea = (const float*)d_in[2];
  const float* W1 = (const float*)d_in[3];
  const float* b1 = (const float*)d_in[4];
  const float* W2 = (const float*)d_in[5];
  const float* b2 = (const float*)d_in[6];
  float* out = (float*)d_out;

  const int E = in_sizes[1] / 2;          // edge_index is [2, E]
  const int ntiles = (E + 127) / 128;     // 128 edges per tile (32 per wave)
  const int grid = ntiles < 512 ? ntiles : 512;  // 2 blocks/CU persistent

  edge_mlp<<<grid, 256, 0, stream>>>(x, ei, ea, W1, b1, W2, b2, out, E, ntiles);
}